// Round 4
// baseline (219.740 us; speedup 1.0000x reference)
//
#include <hip/hip_runtime.h>

#define E_EDGES 3200000
#define N_NODES_K 100000
#define NEG_INF_F (-10000000000.0f)
#define KE_NB (E_EDGES / 256)   // 12500 blocks

// round-to-nearest-even f32 -> bf16 pair packed into one uint (a in low half)
__device__ __forceinline__ unsigned packbf2(float a, float b) {
    unsigned ua = __float_as_uint(a), ub = __float_as_uint(b);
    ua = (ua + 0x7fffu + ((ua >> 16) & 1u)) >> 16;
    ub = (ub + 0x7fffu + ((ub >> 16) & 1u)) & 0xffff0000u;
    return ub | ua;
}

// ---------------------------------------------------------------------------
// K0: one wave — dtype detection
//   flags[0]: edge_index int64 (1) / int32 (0)
//   flags[1]: selection int32 words (0), bytes (1), float32 (2)
// ---------------------------------------------------------------------------
__global__ __launch_bounds__(64) void k_init(const unsigned* ei_w, const unsigned* sel_w,
                                             int* flags) {
    const int lane = threadIdx.x;
    unsigned hw = ei_w[2 * (lane + 1) + 1];  // hi-word if int64 (values < 2^17)
    unsigned long long anyhi = __ballot(hw != 0u);
    unsigned sv = sel_w[lane];
    unsigned long long not01 = __ballot(sv != 0u && sv != 1u);
    unsigned long long notf  = __ballot(sv != 0u && sv != 0x3F800000u);
    if (lane == 0) {
        flags[0] = (anyhi == 0ull) ? 1 : 0;
        flags[1] = (not01 == 0ull) ? 0 : ((notf == 0ull) ? 2 : 1);
    }
}

// ---------------------------------------------------------------------------
// KP: P1[n] = bf16(node_reps[n] @ W1[0:32,:] + b1), P2[n] = bf16(@ W1[32:64,:])
//     rows packed 32 x bf16 = 16 uints = 64 B
// ---------------------------------------------------------------------------
__global__ __launch_bounds__(256) void k_nodeproj(
    const float* __restrict__ nr, const float* __restrict__ W1,
    const float* __restrict__ b1, unsigned* __restrict__ P1b,
    unsigned* __restrict__ P2b) {
    int n = blockIdx.x * 256 + threadIdx.x;
    if (n >= N_NODES_K) return;
    const float4* x4 = (const float4*)(nr + (size_t)n * 32);
    float xr[32];
#pragma unroll
    for (int i = 0; i < 8; ++i) {
        float4 t = x4[i];
        xr[4 * i + 0] = t.x; xr[4 * i + 1] = t.y; xr[4 * i + 2] = t.z; xr[4 * i + 3] = t.w;
    }
    unsigned r1[16], r2[16];
#pragma unroll
    for (int jb = 0; jb < 8; ++jb) {
        const float4 bb = *(const float4*)(b1 + jb * 4);
        float4 a1 = make_float4(bb.x, bb.y, bb.z, bb.w);
        float4 a2 = make_float4(0.f, 0.f, 0.f, 0.f);
#pragma unroll
        for (int k = 0; k < 32; ++k) {
            float xv = xr[k];
            const float4 w1 = *(const float4*)(W1 + (size_t)k * 32 + jb * 4);
            const float4 w2 = *(const float4*)(W1 + (size_t)(32 + k) * 32 + jb * 4);
            a1.x = fmaf(xv, w1.x, a1.x); a1.y = fmaf(xv, w1.y, a1.y);
            a1.z = fmaf(xv, w1.z, a1.z); a1.w = fmaf(xv, w1.w, a1.w);
            a2.x = fmaf(xv, w2.x, a2.x); a2.y = fmaf(xv, w2.y, a2.y);
            a2.z = fmaf(xv, w2.z, a2.z); a2.w = fmaf(xv, w2.w, a2.w);
        }
        r1[2 * jb]     = packbf2(a1.x, a1.y);
        r1[2 * jb + 1] = packbf2(a1.z, a1.w);
        r2[2 * jb]     = packbf2(a2.x, a2.y);
        r2[2 * jb + 1] = packbf2(a2.z, a2.w);
    }
    uint4* o1 = (uint4*)(P1b + (size_t)n * 16);
    uint4* o2 = (uint4*)(P2b + (size_t)n * 16);
#pragma unroll
    for (int i = 0; i < 4; ++i) {
        o1[i] = ((const uint4*)r1)[i];
        o2[i] = ((const uint4*)r2)[i];
    }
}

// ---------------------------------------------------------------------------
// KE: direct per-edge. score = elu(P1[s]+P2[d]+er[e]@W3) . gdiff  (b1 in P1)
//     P rows are bf16-packed (64 B gathers). masked -> NEG_INF.
//     Per-block (max, sum_exp_local) partials.
// ---------------------------------------------------------------------------
__global__ __launch_bounds__(256, 3) void k_edge(
    const float* __restrict__ er_, const float* __restrict__ W1,
    const float* __restrict__ gr, const float* __restrict__ sgr,
    const void* __restrict__ ei_raw, const void* __restrict__ sel_raw,
    const int* __restrict__ flags,
    const unsigned* __restrict__ P1b, const unsigned* __restrict__ P2b,
    float* __restrict__ scores, float* __restrict__ bmax,
    float* __restrict__ bsum) {
    __shared__ float sW[1024];   // W1[64:96][:] row-major [k][j]
    __shared__ float sGd[32];
    __shared__ float sred[8];
    const int tid = threadIdx.x;
    ((float4*)sW)[tid] = ((const float4*)(W1 + 64 * 32))[tid];
    if (tid < 32) sGd[tid] = gr[tid] - sgr[tid];

    const int e = blockIdx.x * 256 + tid;
    const int fei = flags[0], fsel = flags[1];
    bool act;
    if (fsel == 0)      act = ((const int*)sel_raw)[e] == 0;
    else if (fsel == 1) act = ((const unsigned char*)sel_raw)[e] == 0;
    else                act = ((const float*)sel_raw)[e] == 0.0f;

    int s = 0, d = 0;
    if (act) {
        if (fei) {
            int2 vs = ((const int2*)ei_raw)[e];
            int2 vd = ((const int2*)ei_raw)[E_EDGES + e];
            s = vs.x; d = vd.x;
        } else {
            const int* ei = (const int*)ei_raw;
            s = ei[e]; d = ei[E_EDGES + e];
        }
    }
    __syncthreads();   // sW / sGd ready

    float score = NEG_INF_F;
    if (act) {
        // gather bf16 P rows (64 B each)
        uint4 pa[4], pb[4];
        const uint4* q1 = (const uint4*)(P1b + (size_t)s * 16);
        const uint4* q2 = (const uint4*)(P2b + (size_t)d * 16);
#pragma unroll
        for (int i = 0; i < 4; ++i) { pa[i] = q1[i]; pb[i] = q2[i]; }

        float acc[32];
        const unsigned* wa = (const unsigned*)pa;
        const unsigned* wb = (const unsigned*)pb;
#pragma unroll
        for (int t = 0; t < 16; ++t) {
            unsigned u = wa[t], v = wb[t];
            acc[2 * t]     = __uint_as_float(u << 16) + __uint_as_float(v << 16);
            acc[2 * t + 1] = __uint_as_float(u & 0xffff0000u) +
                             __uint_as_float(v & 0xffff0000u);
        }

        const float4* e4 = (const float4*)(er_ + (size_t)e * 32);
#pragma unroll
        for (int kb = 0; kb < 8; ++kb) {
            float4 x = e4[kb];
            const float* xp = (const float*)&x;
#pragma unroll
            for (int kc = 0; kc < 4; ++kc) {
                const float ek = xp[kc];
                const int k = kb * 4 + kc;
#pragma unroll
                for (int jb = 0; jb < 8; ++jb) {
                    const float4 w = *(const float4*)&sW[k * 32 + jb * 4];
                    acc[4 * jb + 0] = fmaf(ek, w.x, acc[4 * jb + 0]);
                    acc[4 * jb + 1] = fmaf(ek, w.y, acc[4 * jb + 1]);
                    acc[4 * jb + 2] = fmaf(ek, w.z, acc[4 * jb + 2]);
                    acc[4 * jb + 3] = fmaf(ek, w.w, acc[4 * jb + 3]);
                }
            }
        }
        float sc = 0.0f;
#pragma unroll
        for (int j = 0; j < 32; ++j) {
            float z = acc[j];
            float h = z > 0.0f ? z : (__expf(z) - 1.0f);
            sc = fmaf(h, sGd[j], sc);
        }
        score = sc;
    }
    scores[e] = score;

    // block max
    float m = score;
#pragma unroll
    for (int off = 32; off > 0; off >>= 1) m = fmaxf(m, __shfl_down(m, off));
    const int lane = tid & 63, wid = tid >> 6;
    if (lane == 0) sred[wid] = m;
    __syncthreads();
    const float mb = fmaxf(fmaxf(sred[0], sred[1]), fmaxf(sred[2], sred[3]));
    // block sum of exp((score - mb)/T)
    float v = __expf((score - mb) * 2.0f);
#pragma unroll
    for (int off = 32; off > 0; off >>= 1) v += __shfl_down(v, off);
    __syncthreads();
    if (lane == 0) sred[4 + wid] = v;
    __syncthreads();
    if (tid == 0) {
        bmax[blockIdx.x] = mb;
        bsum[blockIdx.x] = sred[4] + sred[5] + sred[6] + sred[7];
    }
}

// ---------------------------------------------------------------------------
// KR: one block — global max + rescaled sum over block partials
// ---------------------------------------------------------------------------
__global__ __launch_bounds__(256) void k_reduce(
    const float* __restrict__ bmax, const float* __restrict__ bsum,
    float* __restrict__ mx_out, float* __restrict__ rsum_out) {
    const int tid = threadIdx.x;
    __shared__ float sm[4];
    float m = -3.0e38f;
    for (int i = tid; i < KE_NB; i += 256) m = fmaxf(m, bmax[i]);
#pragma unroll
    for (int off = 32; off > 0; off >>= 1) m = fmaxf(m, __shfl_down(m, off));
    const int lane = tid & 63, wid = tid >> 6;
    if (lane == 0) sm[wid] = m;
    __syncthreads();
    const float M = fmaxf(fmaxf(sm[0], sm[1]), fmaxf(sm[2], sm[3]));
    float s = 0.0f;
    for (int i = tid; i < KE_NB; i += 256)
        s += bsum[i] * __expf((bmax[i] - M) * 2.0f);
#pragma unroll
    for (int off = 32; off > 0; off >>= 1) s += __shfl_down(s, off);
    __syncthreads();
    __shared__ float ss[4];
    if (lane == 0) ss[wid] = s;
    __syncthreads();
    if (tid == 0) {
        *mx_out = M;
        *rsum_out = 1.0f / (ss[0] + ss[1] + ss[2] + ss[3]);
    }
}

// ---------------------------------------------------------------------------
// KF: out = exp((score - M)/T) * rsum
// ---------------------------------------------------------------------------
__global__ __launch_bounds__(256) void k_fin(
    const float* __restrict__ scores, const float* __restrict__ mx,
    const float* __restrict__ rsum, float* __restrict__ out) {
    const int i = blockIdx.x * 256 + threadIdx.x;
    const float M = *mx;
    const float r = *rsum;
    float4 s = ((const float4*)scores)[i];
    float4 o;
    o.x = __expf((s.x - M) * 2.0f) * r;
    o.y = __expf((s.y - M) * 2.0f) * r;
    o.z = __expf((s.z - M) * 2.0f) * r;
    o.w = __expf((s.w - M) * 2.0f) * r;
    ((float4*)out)[i] = o;
}

extern "C" void kernel_launch(void* const* d_in, const int* in_sizes, int n_in,
                              void* d_out, int out_size, void* d_ws, size_t ws_size,
                              hipStream_t stream) {
    const float* node_reps    = (const float*)d_in[0];
    const float* edge_reps    = (const float*)d_in[1];
    const float* graph_rep    = (const float*)d_in[2];
    const float* subgraph_rep = (const float*)d_in[3];
    const float* W1           = (const float*)d_in[4];
    const float* b1           = (const float*)d_in[5];
    const void*  ei           = d_in[6];
    const void*  selp         = d_in[7];
    float* out = (float*)d_out;

    char* ws = (char*)d_ws;
    size_t off = 0;
    unsigned* P1b = (unsigned*)(ws + off); off += (size_t)N_NODES_K * 64;   // 6.4 MB
    unsigned* P2b = (unsigned*)(ws + off); off += (size_t)N_NODES_K * 64;   // 6.4 MB
    float* scores = (float*)(ws + off);    off += (size_t)E_EDGES * 4;      // 12.8 MB
    float* bmax   = (float*)(ws + off);    off += (size_t)KE_NB * 4;
    float* bsum   = (float*)(ws + off);    off += (size_t)KE_NB * 4;
    int*   flags  = (int*)(ws + off);      off += 64;
    float* mx     = (float*)(ws + off);    off += 4;
    float* rsum   = (float*)(ws + off);    off += 4;

    k_init<<<1, 64, 0, stream>>>((const unsigned*)ei, (const unsigned*)selp, flags);
    k_nodeproj<<<(N_NODES_K + 255) / 256, 256, 0, stream>>>(node_reps, W1, b1, P1b, P2b);
    k_edge<<<KE_NB, 256, 0, stream>>>(edge_reps, W1, graph_rep, subgraph_rep,
                                      ei, selp, flags, P1b, P2b, scores, bmax, bsum);
    k_reduce<<<1, 256, 0, stream>>>(bmax, bsum, mx, rsum);
    k_fin<<<E_EDGES / 4 / 256, 256, 0, stream>>>(scores, mx, rsum, out);
}

// Round 5
// 212.599 us; speedup vs baseline: 1.0336x; 1.0336x over previous
//
#include <hip/hip_runtime.h>

#define E_EDGES 3200000
#define N_NODES_K 100000
#define NEG_INF_F (-10000000000.0f)
#define KE_NB (E_EDGES / 256)   // 12500 blocks

typedef __attribute__((ext_vector_type(8))) short short8v;
typedef __attribute__((ext_vector_type(4))) float floatx4;

// round-to-nearest-even f32 -> bf16 pair packed into one uint (a low, b high)
__device__ __forceinline__ unsigned packbf2(float a, float b) {
    unsigned ua = __float_as_uint(a), ub = __float_as_uint(b);
    ua = (ua + 0x7fffu + ((ua >> 16) & 1u)) >> 16;
    ub = (ub + 0x7fffu + ((ub >> 16) & 1u)) & 0xffff0000u;
    return ub | ua;
}

// ---------------------------------------------------------------------------
// K0: one wave — dtype detection
//   flags[0]: edge_index int64 (1) / int32 (0)
//   flags[1]: selection int32 words (0), bytes (1), float32 (2)
// ---------------------------------------------------------------------------
__global__ __launch_bounds__(64) void k_init(const unsigned* ei_w, const unsigned* sel_w,
                                             int* flags) {
    const int lane = threadIdx.x;
    unsigned hw = ei_w[2 * (lane + 1) + 1];  // hi-word if int64 (values < 2^17)
    unsigned long long anyhi = __ballot(hw != 0u);
    unsigned sv = sel_w[lane];
    unsigned long long not01 = __ballot(sv != 0u && sv != 1u);
    unsigned long long notf  = __ballot(sv != 0u && sv != 0x3F800000u);
    if (lane == 0) {
        flags[0] = (anyhi == 0ull) ? 1 : 0;
        flags[1] = (not01 == 0ull) ? 0 : ((notf == 0ull) ? 2 : 1);
    }
}

// ---------------------------------------------------------------------------
// KP: P1c[n][j] = packbf2(p1[j], p1[j+16]), j=0..15  (p1 = nr@W1[0:32]+b1)
//     P2c likewise for W1[32:64], no bias. Row = 16 uints = 64 B.
// ---------------------------------------------------------------------------
__global__ __launch_bounds__(256) void k_nodeproj(
    const float* __restrict__ nr, const float* __restrict__ W1,
    const float* __restrict__ b1, unsigned* __restrict__ P1c,
    unsigned* __restrict__ P2c) {
    int n = blockIdx.x * 256 + threadIdx.x;
    if (n >= N_NODES_K) return;
    const float4* x4 = (const float4*)(nr + (size_t)n * 32);
    float xr[32];
#pragma unroll
    for (int i = 0; i < 8; ++i) {
        float4 t = x4[i];
        xr[4 * i + 0] = t.x; xr[4 * i + 1] = t.y; xr[4 * i + 2] = t.z; xr[4 * i + 3] = t.w;
    }
    float a1[32], a2[32];
#pragma unroll
    for (int j = 0; j < 32; ++j) { a1[j] = b1[j]; a2[j] = 0.0f; }
#pragma unroll
    for (int k = 0; k < 32; ++k) {
        const float xv = xr[k];
#pragma unroll
        for (int jb = 0; jb < 8; ++jb) {
            const float4 w1 = *(const float4*)(W1 + (size_t)k * 32 + jb * 4);
            const float4 w2 = *(const float4*)(W1 + (size_t)(32 + k) * 32 + jb * 4);
            a1[4 * jb + 0] = fmaf(xv, w1.x, a1[4 * jb + 0]);
            a1[4 * jb + 1] = fmaf(xv, w1.y, a1[4 * jb + 1]);
            a1[4 * jb + 2] = fmaf(xv, w1.z, a1[4 * jb + 2]);
            a1[4 * jb + 3] = fmaf(xv, w1.w, a1[4 * jb + 3]);
            a2[4 * jb + 0] = fmaf(xv, w2.x, a2[4 * jb + 0]);
            a2[4 * jb + 1] = fmaf(xv, w2.y, a2[4 * jb + 1]);
            a2[4 * jb + 2] = fmaf(xv, w2.z, a2[4 * jb + 2]);
            a2[4 * jb + 3] = fmaf(xv, w2.w, a2[4 * jb + 3]);
        }
    }
    unsigned r1[16], r2[16];
#pragma unroll
    for (int j = 0; j < 16; ++j) {
        r1[j] = packbf2(a1[j], a1[j + 16]);
        r2[j] = packbf2(a2[j], a2[j + 16]);
    }
    uint4* o1 = (uint4*)(P1c + (size_t)n * 16);
    uint4* o2 = (uint4*)(P2c + (size_t)n * 16);
#pragma unroll
    for (int i = 0; i < 4; ++i) {
        o1[i] = ((const uint4*)r1)[i];
        o2[i] = ((const uint4*)r2)[i];
    }
}

// ---------------------------------------------------------------------------
// KE (MFMA): per block 256 edges. D[j][edge] = W3^T @ er^T via
// mfma_f32_16x16x32_bf16: A = W3^T rows j (persistent, 2 frags for j<16/j>=16),
// B = er tile cols = 16 edges. C layout (m89): col=lane&15=edge,
// row=(lane>>4)*4+r = j. Epilogue: +P1[s]+P2[d] (packed bf16 pairs), ELU,
// dot gdiff (per-lane regs), shfl_xor(16,32) reduce -> per-edge score.
// ---------------------------------------------------------------------------
__global__ __launch_bounds__(256) void k_edge(
    const float* __restrict__ er_, const float* __restrict__ W1,
    const float* __restrict__ gr, const float* __restrict__ sgr,
    const void* __restrict__ ei_raw, const void* __restrict__ sel_raw,
    const int* __restrict__ flags,
    const unsigned* __restrict__ P1c, const unsigned* __restrict__ P2c,
    float* __restrict__ scores, float* __restrict__ bmax,
    float* __restrict__ bsum) {
    __shared__ int sIdx[256];
    __shared__ int dIdx[256];
    __shared__ int aAct[256];
    __shared__ float sred[8];

    const int tid = threadIdx.x;
    const int e0 = blockIdx.x * 256;
    const int fei = flags[0], fsel = flags[1];

    // coalesced stage: selection + endpoint indices
    bool act;
    if (fsel == 0)      act = ((const int*)sel_raw)[e0 + tid] == 0;
    else if (fsel == 1) act = ((const unsigned char*)sel_raw)[e0 + tid] == 0;
    else                act = ((const float*)sel_raw)[e0 + tid] == 0.0f;
    int s, d;
    if (fei) {
        s = ((const int2*)ei_raw)[e0 + tid].x;
        d = ((const int2*)ei_raw)[(size_t)E_EDGES + e0 + tid].x;
    } else {
        s = ((const int*)ei_raw)[e0 + tid];
        d = ((const int*)ei_raw)[E_EDGES + e0 + tid];
    }
    sIdx[tid] = s; dIdx[tid] = d; aAct[tid] = act ? 1 : 0;

    const int lane = tid & 63;
    const int wv   = tid >> 6;     // wave 0..3
    const int col  = lane & 15;    // edge-in-tile (B/C col); j-row for A build
    const int g    = lane >> 4;    // k-group
    const int kb   = g * 8;

    // A-frags (W3^T), built once: elem i = W3[kb+i][row]; row = col (A0), 16+col (A1)
    union { unsigned u[4]; short8v v; } A0, A1;
#pragma unroll
    for (int t = 0; t < 4; ++t) {
        float x0 = W1[(size_t)(64 + kb + 2 * t) * 32 + col];
        float x1 = W1[(size_t)(64 + kb + 2 * t + 1) * 32 + col];
        A0.u[t] = packbf2(x0, x1);
        float y0 = W1[(size_t)(64 + kb + 2 * t) * 32 + 16 + col];
        float y1 = W1[(size_t)(64 + kb + 2 * t + 1) * 32 + 16 + col];
        A1.u[t] = packbf2(y0, y1);
    }
    // gdiff for this lane's j's: j = g*4+r (acc0) and 16+g*4+r (acc1)
    float gd0[4], gd1[4];
#pragma unroll
    for (int r = 0; r < 4; ++r) {
        gd0[r] = gr[g * 4 + r] - sgr[g * 4 + r];
        gd1[r] = gr[16 + g * 4 + r] - sgr[16 + g * 4 + r];
    }
    __syncthreads();

    float s_loc[4];
#pragma unroll
    for (int t = 0; t < 4; ++t) {
        const int erow = (wv * 4 + t) * 16 + col;   // edge within block
        // B-frag: er[e0+erow][kb..kb+7] -> bf16x8 (coalesced 2KB/wave/tile)
        const float4* ep = (const float4*)(er_ + (size_t)(e0 + erow) * 32 + kb);
        float4 xa = ep[0], xb = ep[1];
        union { unsigned u[4]; short8v v; } B;
        B.u[0] = packbf2(xa.x, xa.y); B.u[1] = packbf2(xa.z, xa.w);
        B.u[2] = packbf2(xb.x, xb.y); B.u[3] = packbf2(xb.z, xb.w);

        floatx4 acc0 = {0.f, 0.f, 0.f, 0.f}, acc1 = {0.f, 0.f, 0.f, 0.f};
        acc0 = __builtin_amdgcn_mfma_f32_16x16x32_bf16(A0.v, B.v, acc0, 0, 0, 0);
        acc1 = __builtin_amdgcn_mfma_f32_16x16x32_bf16(A1.v, B.v, acc1, 0, 0, 0);

        // epilogue: gather packed P rows (one uint4 per table per lane)
        const int se = sIdx[erow], de = dIdx[erow];
        uint4 u1 = *(const uint4*)(P1c + (size_t)se * 16 + g * 4);
        uint4 u2 = *(const uint4*)(P2c + (size_t)de * 16 + g * 4);
        const unsigned* pu1 = (const unsigned*)&u1;
        const unsigned* pu2 = (const unsigned*)&u2;
        float part = 0.0f;
#pragma unroll
        for (int r = 0; r < 4; ++r) {
            float z0 = acc0[r] + __uint_as_float(pu1[r] << 16)
                               + __uint_as_float(pu2[r] << 16);
            float z1 = acc1[r] + __uint_as_float(pu1[r] & 0xffff0000u)
                               + __uint_as_float(pu2[r] & 0xffff0000u);
            float h0 = z0 > 0.0f ? z0 : (__expf(z0) - 1.0f);
            float h1 = z1 > 0.0f ? z1 : (__expf(z1) - 1.0f);
            part = fmaf(h0, gd0[r], part);
            part = fmaf(h1, gd1[r], part);
        }
        // sum the 4 k-groups (lanes col, col+16, col+32, col+48)
        part += __shfl_xor(part, 16);
        part += __shfl_xor(part, 32);
        float sc = aAct[erow] ? part : NEG_INF_F;
        s_loc[t] = sc;
        if (g == 0) scores[e0 + erow] = sc;
    }

    // block max
    float m = fmaxf(fmaxf(s_loc[0], s_loc[1]), fmaxf(s_loc[2], s_loc[3]));
#pragma unroll
    for (int off = 32; off > 0; off >>= 1) m = fmaxf(m, __shfl_down(m, off));
    if (lane == 0) sred[wv] = m;
    __syncthreads();
    const float mb = fmaxf(fmaxf(sred[0], sred[1]), fmaxf(sred[2], sred[3]));
    // block sumexp (only g==0 lanes contribute — values are 4x replicated)
    float v = 0.0f;
    if (g == 0) {
#pragma unroll
        for (int t = 0; t < 4; ++t) v += __expf((s_loc[t] - mb) * 2.0f);
    }
#pragma unroll
    for (int off = 32; off > 0; off >>= 1) v += __shfl_down(v, off);
    __syncthreads();
    if (lane == 0) sred[4 + wv] = v;
    __syncthreads();
    if (tid == 0) {
        bmax[blockIdx.x] = mb;
        bsum[blockIdx.x] = sred[4] + sred[5] + sred[6] + sred[7];
    }
}

// ---------------------------------------------------------------------------
// KR: one block — global max + rescaled sum over block partials
// ---------------------------------------------------------------------------
__global__ __launch_bounds__(256) void k_reduce(
    const float* __restrict__ bmax, const float* __restrict__ bsum,
    float* __restrict__ mx_out, float* __restrict__ rsum_out) {
    const int tid = threadIdx.x;
    __shared__ float sm[4];
    float m = -3.0e38f;
    for (int i = tid; i < KE_NB; i += 256) m = fmaxf(m, bmax[i]);
#pragma unroll
    for (int off = 32; off > 0; off >>= 1) m = fmaxf(m, __shfl_down(m, off));
    const int lane = tid & 63, wid = tid >> 6;
    if (lane == 0) sm[wid] = m;
    __syncthreads();
    const float M = fmaxf(fmaxf(sm[0], sm[1]), fmaxf(sm[2], sm[3]));
    float s = 0.0f;
    for (int i = tid; i < KE_NB; i += 256)
        s += bsum[i] * __expf((bmax[i] - M) * 2.0f);
#pragma unroll
    for (int off = 32; off > 0; off >>= 1) s += __shfl_down(s, off);
    __syncthreads();
    __shared__ float ss[4];
    if (lane == 0) ss[wid] = s;
    __syncthreads();
    if (tid == 0) {
        *mx_out = M;
        *rsum_out = 1.0f / (ss[0] + ss[1] + ss[2] + ss[3]);
    }
}

// ---------------------------------------------------------------------------
// KF: out = exp((score - M)/T) * rsum
// ---------------------------------------------------------------------------
__global__ __launch_bounds__(256) void k_fin(
    const float* __restrict__ scores, const float* __restrict__ mx,
    const float* __restrict__ rsum, float* __restrict__ out) {
    const int i = blockIdx.x * 256 + threadIdx.x;
    const float M = *mx;
    const float r = *rsum;
    float4 s = ((const float4*)scores)[i];
    float4 o;
    o.x = __expf((s.x - M) * 2.0f) * r;
    o.y = __expf((s.y - M) * 2.0f) * r;
    o.z = __expf((s.z - M) * 2.0f) * r;
    o.w = __expf((s.w - M) * 2.0f) * r;
    ((float4*)out)[i] = o;
}

extern "C" void kernel_launch(void* const* d_in, const int* in_sizes, int n_in,
                              void* d_out, int out_size, void* d_ws, size_t ws_size,
                              hipStream_t stream) {
    const float* node_reps    = (const float*)d_in[0];
    const float* edge_reps    = (const float*)d_in[1];
    const float* graph_rep    = (const float*)d_in[2];
    const float* subgraph_rep = (const float*)d_in[3];
    const float* W1           = (const float*)d_in[4];
    const float* b1           = (const float*)d_in[5];
    const void*  ei           = d_in[6];
    const void*  selp         = d_in[7];
    float* out = (float*)d_out;

    char* ws = (char*)d_ws;
    size_t off = 0;
    unsigned* P1c = (unsigned*)(ws + off); off += (size_t)N_NODES_K * 64;   // 6.4 MB
    unsigned* P2c = (unsigned*)(ws + off); off += (size_t)N_NODES_K * 64;   // 6.4 MB
    float* scores = (float*)(ws + off);    off += (size_t)E_EDGES * 4;      // 12.8 MB
    float* bmax   = (float*)(ws + off);    off += (size_t)KE_NB * 4;
    float* bsum   = (float*)(ws + off);    off += (size_t)KE_NB * 4;
    int*   flags  = (int*)(ws + off);      off += 64;
    float* mx     = (float*)(ws + off);    off += 4;
    float* rsum   = (float*)(ws + off);    off += 4;

    k_init<<<1, 64, 0, stream>>>((const unsigned*)ei, (const unsigned*)selp, flags);
    k_nodeproj<<<(N_NODES_K + 255) / 256, 256, 0, stream>>>(node_reps, W1, b1, P1c, P2c);
    k_edge<<<KE_NB, 256, 0, stream>>>(edge_reps, W1, graph_rep, subgraph_rep,
                                      ei, selp, flags, P1c, P2c, scores, bmax, bsum);
    k_reduce<<<1, 256, 0, stream>>>(bmax, bsum, mx, rsum);
    k_fin<<<E_EDGES / 4 / 256, 256, 0, stream>>>(scores, mx, rsum, out);
}